// Round 3
// baseline (887.251 us; speedup 1.0000x reference)
//
#include <hip/hip_runtime.h>
#include <hip/hip_bf16.h>
#include <hip/hip_cooperative_groups.h>
#include <stdint.h>

namespace cg = cooperative_groups;

#define N_NODES 100000
#define N_EDGES 1600000
#define IN_DIM 128
#define HEADS 4
#define HID 32
#define HC 128
#define NUM_CLASSES 349
#define NUM_LAYERS 2
#define BN_EPS 1e-5f
#define NEG_SLOPE 0.2f
#define MP 100032     // N_NODES padded to 64 (1563 blocks)

#define NPARAM 144861

// ---- bucket-sort CSR build parameters (cooperative, single kernel) ----
#define NBKT 782                      // ceil(100000/128); bucket = dst >> 7
#define ECHUNK 4096
#define NCHUNK 391                    // = grid size; 391*4096 >= N_EDGES
#define NTOT (NBKT * NCHUNK)          // 305762
#define SCAN_CHUNK 2048
#define SCANB ((NTOT + SCAN_CHUNK - 1) / SCAN_CHUNK)   // 150 (<=256)

// padded packed-B sizes (nt rounded up to multiple of 4 per-wave slices)
#define BP_NT 20                      // 17 used, 3 zero-pad
#define FC_NT 24                      // 22 used, 2 zero-pad
#define BP_ELEMS (BP_NT * 2048)       // 40960
#define FC_ELEMS (FC_NT * 2048)       // 49152
#define PACK_TOTAL (2 * BP_ELEMS + FC_ELEMS)  // 131072

using bf16 = __hip_bfloat16;
typedef __attribute__((ext_vector_type(8))) short short8;
typedef __attribute__((ext_vector_type(4))) float floatx4;

__device__ __forceinline__ float b2f(bf16 v) { return __bfloat162float(v); }

// ------------------------------- runtime dtype detection (+ bnstat clear)
__global__ void detect_dtype(const uint32_t* __restrict__ xw, int* __restrict__ flag,
                             float* __restrict__ bnstat) {
    int lane = threadIdx.x;  // 64 threads
    for (int i = lane; i < 512; i += 64) bnstat[i] = 0.f;
    int insane = 0;
    for (int i = lane; i < 256; i += 64) {
        uint32_t lo = xw[i] & 0xffffu;
        uint32_t e = (lo >> 7) & 0xffu;
        if (lo != 0u && (e < 100u || e > 150u)) insane++;
    }
    for (int off = 32; off > 0; off >>= 1) insane += __shfl_down(insane, off, 64);
    if (lane == 0) *flag = (insane > 64) ? 1 : 0;
}

// all float params -> one contiguous fp32 block (layout = input order)
__global__ void cvt_params(const void* p0, const void* p1, const void* p2, const void* p3,
                           const void* p4, const void* p5, const void* p6, const void* p7,
                           const void* p8, const void* p9, const void* p10,
                           float* __restrict__ out, const int* __restrict__ flag) {
    int i = blockIdx.x * blockDim.x + threadIdx.x;
    if (i >= NPARAM) return;
    bool isf32 = (*flag != 0);
    const void* p; int off;
    if      (i < 32768)  { p = p0;  off = i; }
    else if (i < 65536)  { p = p1;  off = i - 32768; }
    else if (i < 65792)  { p = p2;  off = i - 65536; }
    else if (i < 66048)  { p = p3;  off = i - 65792; }
    else if (i < 66304)  { p = p4;  off = i - 66048; }
    else if (i < 99072)  { p = p5;  off = i - 66304; }
    else if (i < 99328)  { p = p6;  off = i - 99072; }
    else if (i < 99584)  { p = p7;  off = i - 99328; }
    else if (i < 99840)  { p = p8;  off = i - 99584; }
    else if (i < 144512) { p = p9;  off = i - 99840; }
    else                 { p = p10; off = i - 144512; }
    out[i] = isf32 ? ((const float*)p)[off] : b2f(((const bf16*)p)[off]);
}

// -------- one-shot pack of both layers' fused B (with on-the-fly att dots)
// and the fc weight, all into MFMA B-frag layout; pad nt-slices are zeros.
__global__ void pack_all(const float* __restrict__ Wsrc0, const float* __restrict__ Wdst0,
                         const float* __restrict__ asrc0, const float* __restrict__ adst0,
                         const float* __restrict__ linW0, const float* __restrict__ fcW,
                         bf16* __restrict__ Bp0, bf16* __restrict__ Bp1,
                         bf16* __restrict__ fcWp) {
    int gid = blockIdx.x * blockDim.x + threadIdx.x;
    if (gid >= PACK_TOTAL) return;
    if (gid < 2 * BP_ELEMS) {
        int layer = gid / BP_ELEMS;
        int idx = gid - layer * BP_ELEMS;
        const float* Wsrc = Wsrc0 + layer * IN_DIM * HC;
        const float* Wdst = Wdst0 + layer * IN_DIM * HC;
        const float* asrc = asrc0 + layer * HEADS * HID;
        const float* adst = adst0 + layer * HEADS * HID;
        const float* linW = linW0 + layer * IN_DIM * HC;
        int j = idx & 7, lane = (idx >> 3) & 63, kt = (idx >> 9) & 3, nt = idx >> 11;
        int n = nt * 16 + (lane & 15);
        int k = kt * 32 + ((lane >> 4) << 3) + j;
        float v = 0.f;
        if (n < 128) {
            v = Wsrc[k * HC + n];
        } else if (n < 132) {
            int h = n - 128;
            for (int c = 0; c < HID; c++) v += Wsrc[k * HC + h * HID + c] * asrc[h * HID + c];
        } else if (n < 136) {
            int h = n - 132;
            for (int c = 0; c < HID; c++) v += Wdst[k * HC + h * HID + c] * adst[h * HID + c];
        } else if (n < 264) {
            v = linW[k * HC + (n - 136)];
        }
        (layer == 0 ? Bp0 : Bp1)[idx] = __float2bfloat16(v);
    } else {
        int idx = gid - 2 * BP_ELEMS;   // < FC_ELEMS
        int j = idx & 7, lane = (idx >> 3) & 63, kt = (idx >> 9) & 3, nt = idx >> 11;
        int n = nt * 16 + (lane & 15);
        int k = kt * 32 + ((lane >> 4) << 3) + j;
        float v = (n < NUM_CLASSES) ? fcW[k * NUM_CLASSES + n] : 0.f;
        fcWp[idx] = __float2bfloat16(v);
    }
}

// ================================ MFMA GEMMs ================================
// Each wave owns nt in {wave+4j, j<5}; B-frags loaded ONCE into registers and
// reused across 4 row-tiles (cuts per-block B reads 4x). Pad nt-slices (>=17)
// are zeros and produce no stores (col guards).
// MODE=0: A = raw network input (f32 or bf16 per flag); convert during staging,
//         zero-pad rows >= N_NODES.
// MODE=1: A = bf16 h; BN+ReLU applied during staging via per-channel LDS
//         scale/shift (one rsqrt per channel).
template <int MODE>
__global__ __launch_bounds__(256) void gemm_mfma_proj(
    const void* __restrict__ Araw, const int* __restrict__ flag,
    const bf16* __restrict__ Bp,
    bf16* __restrict__ xs, bf16* __restrict__ scA, bf16* __restrict__ xlin,
    const float* __restrict__ gamma, const float* __restrict__ beta,
    const float* __restrict__ bnsum, const float* __restrict__ bnsq) {
    __shared__ bf16 As[64 * 128];
    __shared__ float sc_s[128], sh_s[128];
    int tid = threadIdx.x;
    size_t rowbase = (size_t)blockIdx.x * 64;
    int4* la = (int4*)As;
    if (MODE == 0) {
        bool isf32 = (*flag != 0);
#pragma unroll
        for (int s = 0; s < 4; s++) {
            int idx = s * 256 + tid;
            size_t grow = rowbase + (idx >> 4);
            int cg16 = idx & 15;
            int4 outv = {0, 0, 0, 0};
            if (grow < N_NODES) {
                if (isf32) {
                    const float* xr = (const float*)Araw + grow * 128 + cg16 * 8;
                    float4 f0 = ((const float4*)xr)[0];
                    float4 f1 = ((const float4*)xr)[1];
                    bf16* ov = (bf16*)&outv;
                    ov[0] = __float2bfloat16(f0.x); ov[1] = __float2bfloat16(f0.y);
                    ov[2] = __float2bfloat16(f0.z); ov[3] = __float2bfloat16(f0.w);
                    ov[4] = __float2bfloat16(f1.x); ov[5] = __float2bfloat16(f1.y);
                    ov[6] = __float2bfloat16(f1.z); ov[7] = __float2bfloat16(f1.w);
                } else {
                    outv = ((const int4*)Araw)[grow * 16 + cg16];
                }
            }
            la[idx] = outv;
        }
    } else {
        const float invN = 1.f / (float)N_NODES;
        if (tid < 128) {
            float mu = bnsum[tid] * invN;
            float var = bnsq[tid] * invN - mu * mu;
            float g = gamma[tid] * rsqrtf(var + BN_EPS);
            sc_s[tid] = g;
            sh_s[tid] = beta[tid] - mu * g;
        }
        __syncthreads();
        const bf16* A = (const bf16*)Araw;
        const int4* ga = (const int4*)(A + rowbase * 128);
#pragma unroll
        for (int s = 0; s < 4; s++) {
            int4 raw = ga[s * 256 + tid];
            bf16* hv = (bf16*)&raw;
            int cbase = ((s * 256 + tid) & 15) * 8;
            int4 outv; bf16* ov = (bf16*)&outv;
#pragma unroll
            for (int j = 0; j < 8; j++) {
                int c = cbase + j;
                float v = sc_s[c] * b2f(hv[j]) + sh_s[c];
                ov[j] = __float2bfloat16(v > 0.f ? v : 0.f);
            }
            la[s * 256 + tid] = outv;
        }
    }
    __syncthreads();
    int wave = tid >> 6, lane = tid & 63;
    int colb = lane & 15;
    int acol = (lane >> 4) * 8;
    const short8* bb = (const short8*)Bp + lane;
    short8 bfrag[5][4];
#pragma unroll
    for (int j = 0; j < 5; j++) {
        int nt = wave + 4 * j;
#pragma unroll
        for (int kt = 0; kt < 4; kt++) bfrag[j][kt] = bb[(nt * 4 + kt) * 64];
    }
#pragma unroll
    for (int rt = 0; rt < 4; rt++) {
        int arow = rt * 16 + (lane & 15);
        short8 af[4];
#pragma unroll
        for (int kt = 0; kt < 4; kt++)
            af[kt] = *(const short8*)&As[arow * 128 + kt * 32 + acol];
        int row0 = rt * 16 + (lane >> 4) * 4;
#pragma unroll
        for (int j = 0; j < 5; j++) {
            floatx4 acc = {0.f, 0.f, 0.f, 0.f};
#pragma unroll
            for (int kt = 0; kt < 4; kt++)
                acc = __builtin_amdgcn_mfma_f32_16x16x32_bf16(af[kt], bfrag[j][kt], acc, 0, 0, 0);
            int col = (wave + 4 * j) * 16 + colb;
#pragma unroll
            for (int r = 0; r < 4; r++) {
                size_t row = rowbase + row0 + r;
                bf16 v = __float2bfloat16(acc[r]);
                if (col < 128)       xs[row * HC + col] = v;
                else if (col < 136)  scA[row * 8 + (col - 128)] = v;
                else { int q = col - 136; if (q < 128) xlin[row * HC + q] = v; }
            }
        }
    }
}

// final GEMM: BN+ReLU prologue on h, +bias, dtype-flag store
__global__ __launch_bounds__(256) void gemm_mfma_out(
    const bf16* __restrict__ A, const bf16* __restrict__ Bp,
    const float* __restrict__ bias,
    const float* __restrict__ gamma, const float* __restrict__ beta,
    const float* __restrict__ bnsum, const float* __restrict__ bnsq,
    void* __restrict__ C, const int* __restrict__ flag) {
    __shared__ bf16 As[64 * 128];
    __shared__ float sc_s[128], sh_s[128];
    int tid = threadIdx.x;
    size_t rowbase = (size_t)blockIdx.x * 64;
    const int4* ga = (const int4*)(A + rowbase * 128);
    int4* la = (int4*)As;
    const float invN = 1.f / (float)N_NODES;
    if (tid < 128) {
        float mu = bnsum[tid] * invN;
        float var = bnsq[tid] * invN - mu * mu;
        float g = gamma[tid] * rsqrtf(var + BN_EPS);
        sc_s[tid] = g;
        sh_s[tid] = beta[tid] - mu * g;
    }
    __syncthreads();
#pragma unroll
    for (int s = 0; s < 4; s++) {
        int4 raw = ga[s * 256 + tid];
        bf16* hv = (bf16*)&raw;
        int cbase = ((s * 256 + tid) & 15) * 8;
        int4 outv; bf16* ov = (bf16*)&outv;
#pragma unroll
        for (int j = 0; j < 8; j++) {
            int c = cbase + j;
            float v = sc_s[c] * b2f(hv[j]) + sh_s[c];
            ov[j] = __float2bfloat16(v > 0.f ? v : 0.f);
        }
        la[s * 256 + tid] = outv;
    }
    __syncthreads();
    int wave = tid >> 6, lane = tid & 63;
    int colb = lane & 15;
    int acol = (lane >> 4) * 8;
    const short8* bb = (const short8*)Bp + lane;
    short8 bfrag[6][4];
#pragma unroll
    for (int j = 0; j < 6; j++) {
        int nt = wave + 4 * j;
#pragma unroll
        for (int kt = 0; kt < 4; kt++) bfrag[j][kt] = bb[(nt * 4 + kt) * 64];
    }
    bool isf32 = (*flag != 0);
#pragma unroll
    for (int rt = 0; rt < 4; rt++) {
        int arow = rt * 16 + (lane & 15);
        short8 af[4];
#pragma unroll
        for (int kt = 0; kt < 4; kt++)
            af[kt] = *(const short8*)&As[arow * 128 + kt * 32 + acol];
        int row0 = rt * 16 + (lane >> 4) * 4;
#pragma unroll
        for (int j = 0; j < 6; j++) {
            floatx4 acc = {0.f, 0.f, 0.f, 0.f};
#pragma unroll
            for (int kt = 0; kt < 4; kt++)
                acc = __builtin_amdgcn_mfma_f32_16x16x32_bf16(af[kt], bfrag[j][kt], acc, 0, 0, 0);
            int col = (wave + 4 * j) * 16 + colb;
            if (col < NUM_CLASSES) {
                float bv = bias[col];
#pragma unroll
                for (int r = 0; r < 4; r++) {
                    size_t row = rowbase + row0 + r;
                    if (row < N_NODES) {
                        float v = acc[r] + bv;
                        if (isf32) ((float*)C)[row * NUM_CLASSES + col] = v;
                        else       ((bf16*)C)[row * NUM_CLASSES + col] = __float2bfloat16(v);
                    }
                }
            }
        }
    }
}

// ============== CSR build: single cooperative kernel, 4 phases ==============
// Phase A: per-chunk LDS histogram over NBKT buckets -> cnt[bucket][chunk]
// Phase B: exclusive scan of cnt (bucket-major) -> global write bases
// Phase C: scatter packed (local_dst<<17 | src) to bucket-contiguous positions
// Phase D: per-bucket (2 per block) node-level histogram+scan -> CSR
__global__ __launch_bounds__(256) void csr_coop(
    const int* __restrict__ src, const int* __restrict__ dst,
    int* __restrict__ cnt, int* __restrict__ bsum,
    uint32_t* __restrict__ sorted, int* __restrict__ srcs,
    int* __restrict__ offsets) {
    cg::grid_group grid = cg::this_grid();
    __shared__ int lh[NBKT];
    __shared__ int red[256];
    __shared__ int ts[256];
    __shared__ int pre[256];
    int t = threadIdx.x, b = blockIdx.x;

    // ---- Phase A: histogram of chunk b
    for (int i = t; i < NBKT; i += 256) lh[i] = 0;
    __syncthreads();
    {
        int base = b * ECHUNK;
        int end = base + ECHUNK; if (end > N_EDGES) end = N_EDGES;
        int i = base + t;
        for (; i + 768 < end; i += 1024) {
            int d0 = dst[i], d1 = dst[i + 256], d2 = dst[i + 512], d3 = dst[i + 768];
            atomicAdd(&lh[d0 >> 7], 1); atomicAdd(&lh[d1 >> 7], 1);
            atomicAdd(&lh[d2 >> 7], 1); atomicAdd(&lh[d3 >> 7], 1);
        }
        for (; i < end; i += 256) atomicAdd(&lh[dst[i] >> 7], 1);
    }
    __syncthreads();
    for (int i = t; i < NBKT; i += 256) cnt[i * NCHUNK + b] = lh[i];
    grid.sync();

    // ---- Phase B1: per-scanblock partial sums
    if (b < SCANB) {
        int base = b * SCAN_CHUNK + t * 8;
        int s = 0;
#pragma unroll
        for (int j = 0; j < 8; j++) { int idx = base + j; if (idx < NTOT) s += cnt[idx]; }
        red[t] = s;
        __syncthreads();
        for (int off = 128; off > 0; off >>= 1) {
            if (t < off) red[t] += red[t + off];
            __syncthreads();
        }
        if (t == 0) bsum[b] = red[0];
    }
    grid.sync();

    // ---- Phase B2: in-place exclusive scan
    if (b < SCANB) {
        pre[t] = (t < b) ? bsum[t] : 0;
        int base = b * SCAN_CHUNK + t * 8;
        int c[8]; int mysum = 0;
#pragma unroll
        for (int j = 0; j < 8; j++) { int idx = base + j; c[j] = (idx < NTOT) ? cnt[idx] : 0; mysum += c[j]; }
        ts[t] = mysum;
        __syncthreads();
        for (int off = 128; off > 0; off >>= 1) {
            if (t < off) pre[t] += pre[t + off];
            __syncthreads();
        }
        for (int off = 1; off < 256; off <<= 1) {
            int v = (t >= off) ? ts[t - off] : 0;
            __syncthreads();
            ts[t] += v;
            __syncthreads();
        }
        int run = pre[0] + ts[t] - mysum;
#pragma unroll
        for (int j = 0; j < 8; j++) { int idx = base + j; if (idx < NTOT) { cnt[idx] = run; run += c[j]; } }
    }
    grid.sync();

    // ---- Phase C: scatter chunk b via LDS cursors
    for (int i = t; i < NBKT; i += 256) lh[i] = cnt[i * NCHUNK + b];
    __syncthreads();
    {
        int base = b * ECHUNK;
        int end = base + ECHUNK; if (end > N_EDGES) end = N_EDGES;
        int i = base + t;
        for (; i + 768 < end; i += 1024) {
            int d0 = dst[i],       d1 = dst[i + 256], d2 = dst[i + 512], d3 = dst[i + 768];
            int s0 = src[i],       s1 = src[i + 256], s2 = src[i + 512], s3 = src[i + 768];
            int p0 = atomicAdd(&lh[d0 >> 7], 1);
            int p1 = atomicAdd(&lh[d1 >> 7], 1);
            int p2 = atomicAdd(&lh[d2 >> 7], 1);
            int p3 = atomicAdd(&lh[d3 >> 7], 1);
            sorted[p0] = ((uint32_t)(d0 & 127) << 17) | (uint32_t)s0;
            sorted[p1] = ((uint32_t)(d1 & 127) << 17) | (uint32_t)s1;
            sorted[p2] = ((uint32_t)(d2 & 127) << 17) | (uint32_t)s2;
            sorted[p3] = ((uint32_t)(d3 & 127) << 17) | (uint32_t)s3;
        }
        for (; i < end; i += 256) {
            int d = dst[i];
            int p = atomicAdd(&lh[d >> 7], 1);
            sorted[p] = ((uint32_t)(d & 127) << 17) | (uint32_t)src[i];
        }
    }
    grid.sync();

    // ---- Phase D: two buckets per block (NBKT == 2*NCHUNK)
    int* cnt128 = lh;
    int* sc = lh + 128;
    int* cur = lh + 256;
    for (int bk = b * 2; bk < b * 2 + 2; bk++) {
        int ebeg = cnt[bk * NCHUNK];
        int eend = (bk == NBKT - 1) ? N_EDGES : cnt[(bk + 1) * NCHUNK];
        __syncthreads();
        if (t < 128) cnt128[t] = 0;
        __syncthreads();
        uint32_t buf[10];
        int k = 0;
        for (int e = ebeg + t; e < eend; e += 256) {
            uint32_t u = sorted[e];
            if (k < 10) buf[k] = u;
            k++;
            atomicAdd(&cnt128[u >> 17], 1);
        }
        __syncthreads();
        if (t < 128) sc[t] = cnt128[t];
        __syncthreads();
        for (int off = 1; off < 128; off <<= 1) {
            int v = 0;
            if (t < 128 && t >= off) v = sc[t - off];
            __syncthreads();
            if (t < 128) sc[t] += v;
            __syncthreads();
        }
        if (t < 128) {
            int node = bk * 128 + t;
            if (node < N_NODES) offsets[node] = ebeg + sc[t];   // segment END
            cur[t] = ebeg + sc[t] - cnt128[t];                  // start cursor
        }
        __syncthreads();
        int k2 = 0;
        for (int e = ebeg + t; e < eend; e += 256) {
            uint32_t u = (k2 < 10) ? buf[k2] : sorted[e];
            k2++;
            int ld = (int)(u >> 17);
            int pos = atomicAdd(&cur[ld], 1);
            srcs[pos] = (int)(u & 0x1FFFFu);
        }
    }
}

// ================================ GAT gather ================================
__device__ __forceinline__ void edge_acc(int s, int h, int c0, float s_dst,
                                         const bf16* __restrict__ xs,
                                         const bf16* __restrict__ scA,
                                         float& den, float& n0, float& n1) {
    float sc = b2f(scA[(size_t)s * 8 + h]) + s_dst;
    sc = sc > 0.f ? sc : NEG_SLOPE * sc;
    float e = __expf(sc);
    __hip_bfloat162 xv = *reinterpret_cast<const __hip_bfloat162*>(&xs[(size_t)s * HC + c0]);
    den += e;
    n0 += b2f(xv.x) * e;
    n1 += b2f(xv.y) * e;
}

__global__ __launch_bounds__(256) void gat_gather(
    const int* __restrict__ srcs, const int* __restrict__ offsets,
    const bf16* __restrict__ xs, const bf16* __restrict__ scA,
    const bf16* __restrict__ xlin,
    const float* __restrict__ cbias, const float* __restrict__ lbias,
    bf16* __restrict__ hout) {
    int n = blockIdx.x * 4 + (threadIdx.x >> 6);
    int lane = threadIdx.x & 63;
    int c0 = lane * 2;
    int h = c0 >> 5;
    int beg = (n == 0) ? 0 : offsets[n - 1];
    int end = offsets[n];
    float s_dst = b2f(scA[(size_t)n * 8 + 4 + h]);
    float den = 0.f, n0 = 0.f, n1 = 0.f;
    int i = beg;
    if (i + 7 < end) {
        int s0 = srcs[i],     s1 = srcs[i + 1], s2 = srcs[i + 2], s3 = srcs[i + 3];
        int s4 = srcs[i + 4], s5 = srcs[i + 5], s6 = srcs[i + 6], s7 = srcs[i + 7];
        for (;;) {
            int ni = i + 8;
            bool more = (ni + 7 < end);
            int t0 = 0, t1 = 0, t2 = 0, t3 = 0, t4 = 0, t5 = 0, t6 = 0, t7 = 0;
            if (more) {  // prefetch next group while current computes
                t0 = srcs[ni];     t1 = srcs[ni + 1]; t2 = srcs[ni + 2]; t3 = srcs[ni + 3];
                t4 = srcs[ni + 4]; t5 = srcs[ni + 5]; t6 = srcs[ni + 6]; t7 = srcs[ni + 7];
            }
            edge_acc(s0, h, c0, s_dst, xs, scA, den, n0, n1);
            edge_acc(s1, h, c0, s_dst, xs, scA, den, n0, n1);
            edge_acc(s2, h, c0, s_dst, xs, scA, den, n0, n1);
            edge_acc(s3, h, c0, s_dst, xs, scA, den, n0, n1);
            edge_acc(s4, h, c0, s_dst, xs, scA, den, n0, n1);
            edge_acc(s5, h, c0, s_dst, xs, scA, den, n0, n1);
            edge_acc(s6, h, c0, s_dst, xs, scA, den, n0, n1);
            edge_acc(s7, h, c0, s_dst, xs, scA, den, n0, n1);
            i = ni;
            if (!more) break;
            s0 = t0; s1 = t1; s2 = t2; s3 = t3; s4 = t4; s5 = t5; s6 = t6; s7 = t7;
        }
    }
    for (; i < end; i++)
        edge_acc(srcs[i], h, c0, s_dst, xs, scA, den, n0, n1);
    float r = 1.f / (den + 1e-16f);
    __hip_bfloat162 xl = *reinterpret_cast<const __hip_bfloat162*>(&xlin[(size_t)n * HC + c0]);
    float v0 = n0 * r + b2f(xl.x) + cbias[c0] + lbias[c0];
    float v1 = n1 * r + b2f(xl.y) + cbias[c0 + 1] + lbias[c0 + 1];
    __hip_bfloat162 hv;
    hv.x = __float2bfloat16(v0);
    hv.y = __float2bfloat16(v1);
    *reinterpret_cast<__hip_bfloat162*>(&hout[(size_t)n * HC + c0]) = hv;
}

// ------------------------------------------------------- BN stats (read-only)
__global__ void bn_stats(const bf16* __restrict__ h, float* __restrict__ bnsum,
                         float* __restrict__ bnsq) {
    int c = threadIdx.x & 127;
    int half = threadIdx.x >> 7;
    int r0 = blockIdx.x * 500;
    int rend = r0 + 500; if (rend > N_NODES) rend = N_NODES;
    float s1 = 0.f, s2 = 0.f;
    for (int r = r0 + half; r < rend; r += 2) {
        float v = b2f(h[(size_t)r * HC + c]);
        s1 += v; s2 += v * v;
    }
    atomicAdd(&bnsum[c], s1);
    atomicAdd(&bnsq[c], s2);
}

// ==========================================================================
extern "C" void kernel_launch(void* const* d_in, const int* in_sizes, int n_in,
                              void* d_out, int out_size, void* d_ws, size_t ws_size,
                              hipStream_t stream) {
    const void* x_in = d_in[0];
    const int*  edge = (const int*)d_in[1];
    const int* esrc = edge;
    const int* edst = edge + N_EDGES;

    // ---- d_ws layout ----
    bf16* xbh  = (bf16*)d_ws;                              // MP*128 bf16 (h)
    bf16* xs   = xbh + (size_t)MP * HC;                    // MP*128 bf16
    bf16* scA  = xs + (size_t)MP * HC;                     // MP*8  bf16
    bf16* xlin = scA + (size_t)MP * 8;                     // MP*128 bf16
    bf16* Bp0  = xlin + (size_t)MP * HC;                   // BP_ELEMS bf16
    bf16* Bp1  = Bp0 + BP_ELEMS;                           // BP_ELEMS bf16
    bf16* fcWp = Bp1 + BP_ELEMS;                           // FC_ELEMS bf16
    float* bnstat = (float*)(fcWp + FC_ELEMS);             // 4*128 f32 [s0,q0,s1,q1]
    int*   flag  = (int*)(bnstat + 512);                   // 1 (+pad)
    int*   bsum  = flag + 4;                               // SCANB (150)
    float* parms = (float*)(bsum + SCANB + 2);             // NPARAM f32
    // param block offsets (input order)
    float* Wsrc_f  = parms;             // 2*16384
    float* Wdst_f  = parms + 32768;
    float* asrc_f  = parms + 65536;
    float* adst_f  = parms + 65792;
    float* cbias_f = parms + 66048;
    float* linW_f  = parms + 66304;
    float* linb_f  = parms + 99072;
    float* gamma_f = parms + 99328;
    float* beta_f  = parms + 99584;
    float* fcW_f   = parms + 99840;     // 128*349
    float* fcb_f   = parms + 144512;    // 349

    // ---- d_out scratch (dead before gemm_mfma_out writes) ----
    int* srcs    = (int*)d_out;                            // 6.4 MB
    int* offsets = srcs + N_EDGES;                         // 0.4 MB (segment ends)
    uint32_t* sorted = (uint32_t*)(offsets + N_NODES);     // 6.4 MB bucket-sorted packed edges
    int* cnt = (int*)(sorted + N_EDGES);                   // NTOT (1.2 MB) count/base matrix

    detect_dtype<<<1, 64, 0, stream>>>((const uint32_t*)x_in, flag, bnstat);

    cvt_params<<<(NPARAM + 255) / 256, 256, 0, stream>>>(
        d_in[2], d_in[3], d_in[4], d_in[5], d_in[6], d_in[7], d_in[8],
        d_in[9], d_in[10], d_in[11], d_in[12], parms, flag);

    // ---- CSR build: one cooperative kernel (hist/scan/scatter/bucket-CSR) ----
    {
        void* args[] = { (void*)&esrc, (void*)&edst, (void*)&cnt, (void*)&bsum,
                         (void*)&sorted, (void*)&srcs, (void*)&offsets };
        hipLaunchCooperativeKernel((void*)csr_coop, dim3(NCHUNK), dim3(256),
                                   args, 0, stream);
    }

    pack_all<<<(PACK_TOTAL + 255) / 256, 256, 0, stream>>>(
        Wsrc_f, Wdst_f, asrc_f, adst_f, linW_f, fcW_f, Bp0, Bp1, fcWp);

    for (int layer = 0; layer < NUM_LAYERS; layer++) {
        const int boff = layer * HC;
        float* bns = bnstat + layer * 256;       // sum
        float* bnq = bns + 128;                  // sumsq

        if (layer == 0) {
            gemm_mfma_proj<0><<<MP / 64, 256, 0, stream>>>(
                x_in, flag, Bp0, xs, scA, xlin, nullptr, nullptr, nullptr, nullptr);
        } else {
            float* pbns = bnstat + (layer - 1) * 256;
            gemm_mfma_proj<1><<<MP / 64, 256, 0, stream>>>(
                xbh, nullptr, Bp1, xs, scA, xlin,
                gamma_f + (layer - 1) * HC, beta_f + (layer - 1) * HC,
                pbns, pbns + 128);
        }

        // h overwrites the xbh region (stream-ordered; gat_gather reads only xs/scA/xlin)
        gat_gather<<<N_NODES / 4, 256, 0, stream>>>(
            srcs, offsets, xs, scA, xlin, cbias_f + boff, linb_f + boff, xbh);

        bn_stats<<<200, 256, 0, stream>>>(xbh, bns, bnq);
    }

    gemm_mfma_out<<<MP / 64, 256, 0, stream>>>(
        xbh, fcWp, fcb_f, gamma_f + HC, beta_f + HC,
        bnstat + 256, bnstat + 256 + 128, d_out, flag);
}

// Round 4
// 667.086 us; speedup vs baseline: 1.3300x; 1.3300x over previous
//
#include <hip/hip_runtime.h>
#include <hip/hip_bf16.h>
#include <stdint.h>

#define N_NODES 100000
#define N_EDGES 1600000
#define IN_DIM 128
#define HEADS 4
#define HID 32
#define HC 128
#define NUM_CLASSES 349
#define NUM_LAYERS 2
#define BN_EPS 1e-5f
#define NEG_SLOPE 0.2f
#define MP 100032     // N_NODES padded to 64 (1563 blocks)

#define NPARAM 144861

// ---- bucket-sort CSR build parameters ----
#define NBKT 782                      // ceil(100000/128); bucket = dst >> 7
#define ECHUNK 4096
#define NCHUNK ((N_EDGES + ECHUNK - 1) / ECHUNK)   // 391
#define NTOT (NBKT * NCHUNK)                        // 305762
#define SCAN_CHUNK 2048
#define SCANB ((NTOT + SCAN_CHUNK - 1) / SCAN_CHUNK)  // 150 (<=256)

// padded packed-B sizes (nt rounded up to multiple of 4 per-wave slices)
#define BP_NT 20                      // 17 used, 3 zero-pad
#define FC_NT 24                      // 22 used, 2 zero-pad
#define BP_ELEMS (BP_NT * 2048)       // 40960
#define FC_ELEMS (FC_NT * 2048)       // 49152
#define PACK_TOTAL (2 * BP_ELEMS + FC_ELEMS)  // 131072

using bf16 = __hip_bfloat16;
typedef __attribute__((ext_vector_type(8))) short short8;
typedef __attribute__((ext_vector_type(4))) float floatx4;

__device__ __forceinline__ float b2f(bf16 v) { return __bfloat162float(v); }

// ------------------------------- runtime dtype detection (+ bnstat clear)
__global__ void detect_dtype(const uint32_t* __restrict__ xw, int* __restrict__ flag,
                             float* __restrict__ bnstat) {
    int lane = threadIdx.x;  // 64 threads
    for (int i = lane; i < 512; i += 64) bnstat[i] = 0.f;
    int insane = 0;
    for (int i = lane; i < 256; i += 64) {
        uint32_t lo = xw[i] & 0xffffu;
        uint32_t e = (lo >> 7) & 0xffu;
        if (lo != 0u && (e < 100u || e > 150u)) insane++;
    }
    for (int off = 32; off > 0; off >>= 1) insane += __shfl_down(insane, off, 64);
    if (lane == 0) *flag = (insane > 64) ? 1 : 0;
}

// all float params -> one contiguous fp32 block (layout = input order)
__global__ void cvt_params(const void* p0, const void* p1, const void* p2, const void* p3,
                           const void* p4, const void* p5, const void* p6, const void* p7,
                           const void* p8, const void* p9, const void* p10,
                           float* __restrict__ out, const int* __restrict__ flag) {
    int i = blockIdx.x * blockDim.x + threadIdx.x;
    if (i >= NPARAM) return;
    bool isf32 = (*flag != 0);
    const void* p; int off;
    if      (i < 32768)  { p = p0;  off = i; }
    else if (i < 65536)  { p = p1;  off = i - 32768; }
    else if (i < 65792)  { p = p2;  off = i - 65536; }
    else if (i < 66048)  { p = p3;  off = i - 65792; }
    else if (i < 66304)  { p = p4;  off = i - 66048; }
    else if (i < 99072)  { p = p5;  off = i - 66304; }
    else if (i < 99328)  { p = p6;  off = i - 99072; }
    else if (i < 99584)  { p = p7;  off = i - 99328; }
    else if (i < 99840)  { p = p8;  off = i - 99584; }
    else if (i < 144512) { p = p9;  off = i - 99840; }
    else                 { p = p10; off = i - 144512; }
    out[i] = isf32 ? ((const float*)p)[off] : b2f(((const bf16*)p)[off]);
}

// -------- one-shot pack of both layers' fused B (with on-the-fly att dots)
// and the fc weight, all into MFMA B-frag layout; pad nt-slices are zeros.
__global__ void pack_all(const float* __restrict__ Wsrc0, const float* __restrict__ Wdst0,
                         const float* __restrict__ asrc0, const float* __restrict__ adst0,
                         const float* __restrict__ linW0, const float* __restrict__ fcW,
                         bf16* __restrict__ Bp0, bf16* __restrict__ Bp1,
                         bf16* __restrict__ fcWp) {
    int gid = blockIdx.x * blockDim.x + threadIdx.x;
    if (gid >= PACK_TOTAL) return;
    if (gid < 2 * BP_ELEMS) {
        int layer = gid / BP_ELEMS;
        int idx = gid - layer * BP_ELEMS;
        const float* Wsrc = Wsrc0 + layer * IN_DIM * HC;
        const float* Wdst = Wdst0 + layer * IN_DIM * HC;
        const float* asrc = asrc0 + layer * HEADS * HID;
        const float* adst = adst0 + layer * HEADS * HID;
        const float* linW = linW0 + layer * IN_DIM * HC;
        int j = idx & 7, lane = (idx >> 3) & 63, kt = (idx >> 9) & 3, nt = idx >> 11;
        int n = nt * 16 + (lane & 15);
        int k = kt * 32 + ((lane >> 4) << 3) + j;
        float v = 0.f;
        if (n < 128) {
            v = Wsrc[k * HC + n];
        } else if (n < 132) {
            int h = n - 128;
            for (int c = 0; c < HID; c++) v += Wsrc[k * HC + h * HID + c] * asrc[h * HID + c];
        } else if (n < 136) {
            int h = n - 132;
            for (int c = 0; c < HID; c++) v += Wdst[k * HC + h * HID + c] * adst[h * HID + c];
        } else if (n < 264) {
            v = linW[k * HC + (n - 136)];
        }
        (layer == 0 ? Bp0 : Bp1)[idx] = __float2bfloat16(v);
    } else {
        int idx = gid - 2 * BP_ELEMS;   // < FC_ELEMS
        int j = idx & 7, lane = (idx >> 3) & 63, kt = (idx >> 9) & 3, nt = idx >> 11;
        int n = nt * 16 + (lane & 15);
        int k = kt * 32 + ((lane >> 4) << 3) + j;
        float v = (n < NUM_CLASSES) ? fcW[k * NUM_CLASSES + n] : 0.f;
        fcWp[idx] = __float2bfloat16(v);
    }
}

// ================================ MFMA GEMMs ================================
// Each wave owns nt in {wave+4j}; B-frags loaded ONCE into registers and
// reused across 4 row-tiles. Pad nt-slices are zeros (no stores: col guards).
// MODE=0: A = raw network input (f32 or bf16 per flag); convert during staging.
// MODE=1: A = bf16 h; BN+ReLU applied during staging via per-channel LDS
//         scale/shift (one rsqrt per channel).
template <int MODE>
__global__ __launch_bounds__(256) void gemm_mfma_proj(
    const void* __restrict__ Araw, const int* __restrict__ flag,
    const bf16* __restrict__ Bp,
    bf16* __restrict__ xs, bf16* __restrict__ scA, bf16* __restrict__ xlin,
    const float* __restrict__ gamma, const float* __restrict__ beta,
    const float* __restrict__ bnsum, const float* __restrict__ bnsq) {
    __shared__ bf16 As[64 * 128];
    __shared__ float sc_s[128], sh_s[128];
    int tid = threadIdx.x;
    size_t rowbase = (size_t)blockIdx.x * 64;
    int4* la = (int4*)As;
    if (MODE == 0) {
        bool isf32 = (*flag != 0);
#pragma unroll
        for (int s = 0; s < 4; s++) {
            int idx = s * 256 + tid;
            size_t grow = rowbase + (idx >> 4);
            int cg16 = idx & 15;
            int4 outv = {0, 0, 0, 0};
            if (grow < N_NODES) {
                if (isf32) {
                    const float* xr = (const float*)Araw + grow * 128 + cg16 * 8;
                    float4 f0 = ((const float4*)xr)[0];
                    float4 f1 = ((const float4*)xr)[1];
                    bf16* ov = (bf16*)&outv;
                    ov[0] = __float2bfloat16(f0.x); ov[1] = __float2bfloat16(f0.y);
                    ov[2] = __float2bfloat16(f0.z); ov[3] = __float2bfloat16(f0.w);
                    ov[4] = __float2bfloat16(f1.x); ov[5] = __float2bfloat16(f1.y);
                    ov[6] = __float2bfloat16(f1.z); ov[7] = __float2bfloat16(f1.w);
                } else {
                    outv = ((const int4*)Araw)[grow * 16 + cg16];
                }
            }
            la[idx] = outv;
        }
    } else {
        const float invN = 1.f / (float)N_NODES;
        if (tid < 128) {
            float mu = bnsum[tid] * invN;
            float var = bnsq[tid] * invN - mu * mu;
            float g = gamma[tid] * rsqrtf(var + BN_EPS);
            sc_s[tid] = g;
            sh_s[tid] = beta[tid] - mu * g;
        }
        __syncthreads();
        const bf16* A = (const bf16*)Araw;
        const int4* ga = (const int4*)(A + rowbase * 128);
#pragma unroll
        for (int s = 0; s < 4; s++) {
            int4 raw = ga[s * 256 + tid];
            bf16* hv = (bf16*)&raw;
            int cbase = ((s * 256 + tid) & 15) * 8;
            int4 outv; bf16* ov = (bf16*)&outv;
#pragma unroll
            for (int j = 0; j < 8; j++) {
                int c = cbase + j;
                float v = sc_s[c] * b2f(hv[j]) + sh_s[c];
                ov[j] = __float2bfloat16(v > 0.f ? v : 0.f);
            }
            la[s * 256 + tid] = outv;
        }
    }
    __syncthreads();
    int wave = tid >> 6, lane = tid & 63;
    int colb = lane & 15;
    int acol = (lane >> 4) * 8;
    const short8* bb = (const short8*)Bp + lane;
    short8 bfrag[5][4];
#pragma unroll
    for (int j = 0; j < 5; j++) {
        int nt = wave + 4 * j;
#pragma unroll
        for (int kt = 0; kt < 4; kt++) bfrag[j][kt] = bb[(nt * 4 + kt) * 64];
    }
#pragma unroll
    for (int rt = 0; rt < 4; rt++) {
        int arow = rt * 16 + (lane & 15);
        short8 af[4];
#pragma unroll
        for (int kt = 0; kt < 4; kt++)
            af[kt] = *(const short8*)&As[arow * 128 + kt * 32 + acol];
        int row0 = rt * 16 + (lane >> 4) * 4;
#pragma unroll
        for (int j = 0; j < 5; j++) {
            floatx4 acc = {0.f, 0.f, 0.f, 0.f};
#pragma unroll
            for (int kt = 0; kt < 4; kt++)
                acc = __builtin_amdgcn_mfma_f32_16x16x32_bf16(af[kt], bfrag[j][kt], acc, 0, 0, 0);
            int col = (wave + 4 * j) * 16 + colb;
#pragma unroll
            for (int r = 0; r < 4; r++) {
                size_t row = rowbase + row0 + r;
                bf16 v = __float2bfloat16(acc[r]);
                if (col < 128)       xs[row * HC + col] = v;
                else if (col < 136)  scA[row * 8 + (col - 128)] = v;
                else { int q = col - 136; if (q < 128) xlin[row * HC + q] = v; }
            }
        }
    }
}

// final GEMM: BN+ReLU prologue on h, +bias, dtype-flag store
__global__ __launch_bounds__(256) void gemm_mfma_out(
    const bf16* __restrict__ A, const bf16* __restrict__ Bp,
    const float* __restrict__ bias,
    const float* __restrict__ gamma, const float* __restrict__ beta,
    const float* __restrict__ bnsum, const float* __restrict__ bnsq,
    void* __restrict__ C, const int* __restrict__ flag) {
    __shared__ bf16 As[64 * 128];
    __shared__ float sc_s[128], sh_s[128];
    int tid = threadIdx.x;
    size_t rowbase = (size_t)blockIdx.x * 64;
    const int4* ga = (const int4*)(A + rowbase * 128);
    int4* la = (int4*)As;
    const float invN = 1.f / (float)N_NODES;
    if (tid < 128) {
        float mu = bnsum[tid] * invN;
        float var = bnsq[tid] * invN - mu * mu;
        float g = gamma[tid] * rsqrtf(var + BN_EPS);
        sc_s[tid] = g;
        sh_s[tid] = beta[tid] - mu * g;
    }
    __syncthreads();
#pragma unroll
    for (int s = 0; s < 4; s++) {
        int4 raw = ga[s * 256 + tid];
        bf16* hv = (bf16*)&raw;
        int cbase = ((s * 256 + tid) & 15) * 8;
        int4 outv; bf16* ov = (bf16*)&outv;
#pragma unroll
        for (int j = 0; j < 8; j++) {
            int c = cbase + j;
            float v = sc_s[c] * b2f(hv[j]) + sh_s[c];
            ov[j] = __float2bfloat16(v > 0.f ? v : 0.f);
        }
        la[s * 256 + tid] = outv;
    }
    __syncthreads();
    int wave = tid >> 6, lane = tid & 63;
    int colb = lane & 15;
    int acol = (lane >> 4) * 8;
    const short8* bb = (const short8*)Bp + lane;
    short8 bfrag[6][4];
#pragma unroll
    for (int j = 0; j < 6; j++) {
        int nt = wave + 4 * j;
#pragma unroll
        for (int kt = 0; kt < 4; kt++) bfrag[j][kt] = bb[(nt * 4 + kt) * 64];
    }
    bool isf32 = (*flag != 0);
#pragma unroll
    for (int rt = 0; rt < 4; rt++) {
        int arow = rt * 16 + (lane & 15);
        short8 af[4];
#pragma unroll
        for (int kt = 0; kt < 4; kt++)
            af[kt] = *(const short8*)&As[arow * 128 + kt * 32 + acol];
        int row0 = rt * 16 + (lane >> 4) * 4;
#pragma unroll
        for (int j = 0; j < 6; j++) {
            floatx4 acc = {0.f, 0.f, 0.f, 0.f};
#pragma unroll
            for (int kt = 0; kt < 4; kt++)
                acc = __builtin_amdgcn_mfma_f32_16x16x32_bf16(af[kt], bfrag[j][kt], acc, 0, 0, 0);
            int col = (wave + 4 * j) * 16 + colb;
            if (col < NUM_CLASSES) {
                float bv = bias[col];
#pragma unroll
                for (int r = 0; r < 4; r++) {
                    size_t row = rowbase + row0 + r;
                    if (row < N_NODES) {
                        float v = acc[r] + bv;
                        if (isf32) ((float*)C)[row * NUM_CLASSES + col] = v;
                        else       ((bf16*)C)[row * NUM_CLASSES + col] = __float2bfloat16(v);
                    }
                }
            }
        }
    }
}

// ======================= CSR build: atomic-free bucket sort =======================
// (multi-kernel: stream order is the dependency; each phase gets its natural grid)
// Pass 1: per-chunk LDS histogram over NBKT coarse buckets (dst>>7).
__global__ __launch_bounds__(256) void bucket_hist(const int* __restrict__ dst,
                                                   int* __restrict__ cnt) {
    __shared__ int h[NBKT];
    int t = threadIdx.x;
    for (int i = t; i < NBKT; i += 256) h[i] = 0;
    __syncthreads();
    int base = blockIdx.x * ECHUNK;
    int end = base + ECHUNK; if (end > N_EDGES) end = N_EDGES;
    int i = base + t;
    for (; i + 768 < end; i += 1024) {
        int d0 = dst[i], d1 = dst[i + 256], d2 = dst[i + 512], d3 = dst[i + 768];
        atomicAdd(&h[d0 >> 7], 1); atomicAdd(&h[d1 >> 7], 1);
        atomicAdd(&h[d2 >> 7], 1); atomicAdd(&h[d3 >> 7], 1);
    }
    for (; i < end; i += 256) atomicAdd(&h[dst[i] >> 7], 1);
    __syncthreads();
    // bucket-major layout so a flat exclusive scan gives (bucket,chunk) bases
    for (int i2 = t; i2 < NBKT; i2 += 256)
        cnt[i2 * NCHUNK + blockIdx.x] = h[i2];
}

// two-kernel exclusive scan: partial block sums, then per-block self-prefix
__global__ void scan_partial(const int* __restrict__ counts, int* __restrict__ bsum, int n) {
    __shared__ int red[256];
    int t = threadIdx.x;
    int base = blockIdx.x * SCAN_CHUNK + t * 8;
    int s = 0;
#pragma unroll
    for (int j = 0; j < 8; j++) {
        int idx = base + j;
        if (idx < n) s += counts[idx];
    }
    red[t] = s;
    __syncthreads();
    for (int off = 128; off > 0; off >>= 1) {
        if (t < off) red[t] += red[t + off];
        __syncthreads();
    }
    if (t == 0) bsum[blockIdx.x] = red[0];
}

// in-place: counts -> exclusive-scan offsets; block offset computed from raw
// bsum partials by an in-block reduction (no serial scan kernel)
__global__ void scan_final(int* __restrict__ counts, const int* __restrict__ bsum, int n) {
    __shared__ int ts[256];
    __shared__ int pre[256];
    int t = threadIdx.x;
    pre[t] = (t < (int)blockIdx.x) ? bsum[t] : 0;   // blockIdx.x <= SCANB-1 < 256
    int base = blockIdx.x * SCAN_CHUNK + t * 8;
    int c[8];
    int mysum = 0;
#pragma unroll
    for (int j = 0; j < 8; j++) {
        int idx = base + j;
        c[j] = (idx < n) ? counts[idx] : 0;
        mysum += c[j];
    }
    ts[t] = mysum;
    __syncthreads();
    for (int off = 128; off > 0; off >>= 1) {
        if (t < off) pre[t] += pre[t + off];
        __syncthreads();
    }
    for (int off = 1; off < 256; off <<= 1) {
        int v = (t >= off) ? ts[t - off] : 0;
        __syncthreads();
        ts[t] += v;
        __syncthreads();
    }
    int run = pre[0] + ts[t] - mysum;
#pragma unroll
    for (int j = 0; j < 8; j++) {
        int idx = base + j;
        if (idx < n) {
            counts[idx] = run;
            run += c[j];
        }
    }
}

// Pass 3: replay chunk, place packed (local_dst<<17 | src) at bucket-contiguous
// positions via LDS cursors.
__global__ __launch_bounds__(256) void bucket_scatter(const int* __restrict__ src,
                                                      const int* __restrict__ dst,
                                                      const int* __restrict__ cntscan,
                                                      uint32_t* __restrict__ sorted) {
    __shared__ int cur[NBKT];
    int t = threadIdx.x;
    for (int i = t; i < NBKT; i += 256)
        cur[i] = cntscan[i * NCHUNK + blockIdx.x];
    __syncthreads();
    int base = blockIdx.x * ECHUNK;
    int end = base + ECHUNK; if (end > N_EDGES) end = N_EDGES;
    int i = base + t;
    for (; i + 768 < end; i += 1024) {
        int d0 = dst[i],       d1 = dst[i + 256], d2 = dst[i + 512], d3 = dst[i + 768];
        int s0 = src[i],       s1 = src[i + 256], s2 = src[i + 512], s3 = src[i + 768];
        int p0 = atomicAdd(&cur[d0 >> 7], 1);
        int p1 = atomicAdd(&cur[d1 >> 7], 1);
        int p2 = atomicAdd(&cur[d2 >> 7], 1);
        int p3 = atomicAdd(&cur[d3 >> 7], 1);
        sorted[p0] = ((uint32_t)(d0 & 127) << 17) | (uint32_t)s0;
        sorted[p1] = ((uint32_t)(d1 & 127) << 17) | (uint32_t)s1;
        sorted[p2] = ((uint32_t)(d2 & 127) << 17) | (uint32_t)s2;
        sorted[p3] = ((uint32_t)(d3 & 127) << 17) | (uint32_t)s3;
    }
    for (; i < end; i += 256) {
        int d = dst[i];
        int p = atomicAdd(&cur[d >> 7], 1);
        sorted[p] = ((uint32_t)(d & 127) << 17) | (uint32_t)src[i];
    }
}

// Pass 4: one block per bucket. LDS histogram + scan -> per-node CSR offsets;
// in-block cursor scatter of srcs into an 8 KB contiguous region.
__global__ __launch_bounds__(256) void bucket_csr(const uint32_t* __restrict__ sorted,
                                                  const int* __restrict__ cntscan,
                                                  int* __restrict__ srcs,
                                                  int* __restrict__ offsets) {
    __shared__ int cnt128[128];
    __shared__ int sc[128];
    __shared__ int cur[128];
    int b = blockIdx.x, t = threadIdx.x;
    int ebeg = cntscan[b * NCHUNK];
    int eend = (b == NBKT - 1) ? N_EDGES : cntscan[(b + 1) * NCHUNK];
    if (t < 128) cnt128[t] = 0;
    __syncthreads();
    uint32_t buf[10];
    int k = 0;
    for (int e = ebeg + t; e < eend; e += 256) {
        uint32_t u = sorted[e];
        if (k < 10) buf[k] = u;
        k++;
        atomicAdd(&cnt128[u >> 17], 1);
    }
    __syncthreads();
    if (t < 128) sc[t] = cnt128[t];
    __syncthreads();
    for (int off = 1; off < 128; off <<= 1) {
        int v = 0;
        if (t < 128 && t >= off) v = sc[t - off];
        __syncthreads();
        if (t < 128) sc[t] += v;
        __syncthreads();
    }
    // sc = inclusive scan of per-node counts
    if (t < 128) {
        int node = b * 128 + t;
        if (node < N_NODES) offsets[node] = ebeg + sc[t];   // segment END, as gather expects
        cur[t] = ebeg + sc[t] - cnt128[t];                  // exclusive start cursor
    }
    __syncthreads();
    int k2 = 0;
    for (int e = ebeg + t; e < eend; e += 256) {
        uint32_t u = (k2 < 10) ? buf[k2] : sorted[e];
        k2++;
        int ld = (int)(u >> 17);
        int pos = atomicAdd(&cur[ld], 1);
        srcs[pos] = (int)(u & 0x1FFFFu);
    }
}

// ================================ GAT gather ================================
__device__ __forceinline__ void edge_acc(int s, int h, int c0, float s_dst,
                                         const bf16* __restrict__ xs,
                                         const bf16* __restrict__ scA,
                                         float& den, float& n0, float& n1) {
    float sc = b2f(scA[(size_t)s * 8 + h]) + s_dst;
    sc = sc > 0.f ? sc : NEG_SLOPE * sc;
    float e = __expf(sc);
    __hip_bfloat162 xv = *reinterpret_cast<const __hip_bfloat162*>(&xs[(size_t)s * HC + c0]);
    den += e;
    n0 += b2f(xv.x) * e;
    n1 += b2f(xv.y) * e;
}

__global__ __launch_bounds__(256) void gat_gather(
    const int* __restrict__ srcs, const int* __restrict__ offsets,
    const bf16* __restrict__ xs, const bf16* __restrict__ scA,
    const bf16* __restrict__ xlin,
    const float* __restrict__ cbias, const float* __restrict__ lbias,
    bf16* __restrict__ hout) {
    int n = blockIdx.x * 4 + (threadIdx.x >> 6);
    int lane = threadIdx.x & 63;
    int c0 = lane * 2;
    int h = c0 >> 5;
    int beg = (n == 0) ? 0 : offsets[n - 1];
    int end = offsets[n];
    float s_dst = b2f(scA[(size_t)n * 8 + 4 + h]);
    float den = 0.f, n0 = 0.f, n1 = 0.f;
    int i = beg;
    if (i + 7 < end) {
        int s0 = srcs[i],     s1 = srcs[i + 1], s2 = srcs[i + 2], s3 = srcs[i + 3];
        int s4 = srcs[i + 4], s5 = srcs[i + 5], s6 = srcs[i + 6], s7 = srcs[i + 7];
        for (;;) {
            int ni = i + 8;
            bool more = (ni + 7 < end);
            int t0 = 0, t1 = 0, t2 = 0, t3 = 0, t4 = 0, t5 = 0, t6 = 0, t7 = 0;
            if (more) {  // prefetch next group while current computes
                t0 = srcs[ni];     t1 = srcs[ni + 1]; t2 = srcs[ni + 2]; t3 = srcs[ni + 3];
                t4 = srcs[ni + 4]; t5 = srcs[ni + 5]; t6 = srcs[ni + 6]; t7 = srcs[ni + 7];
            }
            edge_acc(s0, h, c0, s_dst, xs, scA, den, n0, n1);
            edge_acc(s1, h, c0, s_dst, xs, scA, den, n0, n1);
            edge_acc(s2, h, c0, s_dst, xs, scA, den, n0, n1);
            edge_acc(s3, h, c0, s_dst, xs, scA, den, n0, n1);
            edge_acc(s4, h, c0, s_dst, xs, scA, den, n0, n1);
            edge_acc(s5, h, c0, s_dst, xs, scA, den, n0, n1);
            edge_acc(s6, h, c0, s_dst, xs, scA, den, n0, n1);
            edge_acc(s7, h, c0, s_dst, xs, scA, den, n0, n1);
            i = ni;
            if (!more) break;
            s0 = t0; s1 = t1; s2 = t2; s3 = t3; s4 = t4; s5 = t5; s6 = t6; s7 = t7;
        }
    }
    for (; i < end; i++)
        edge_acc(srcs[i], h, c0, s_dst, xs, scA, den, n0, n1);
    float r = 1.f / (den + 1e-16f);
    __hip_bfloat162 xl = *reinterpret_cast<const __hip_bfloat162*>(&xlin[(size_t)n * HC + c0]);
    float v0 = n0 * r + b2f(xl.x) + cbias[c0] + lbias[c0];
    float v1 = n1 * r + b2f(xl.y) + cbias[c0 + 1] + lbias[c0 + 1];
    __hip_bfloat162 hv;
    hv.x = __float2bfloat16(v0);
    hv.y = __float2bfloat16(v1);
    *reinterpret_cast<__hip_bfloat162*>(&hout[(size_t)n * HC + c0]) = hv;
}

// ------------------------------------------------------- BN stats (read-only)
__global__ void bn_stats(const bf16* __restrict__ h, float* __restrict__ bnsum,
                         float* __restrict__ bnsq) {
    int c = threadIdx.x & 127;
    int half = threadIdx.x >> 7;
    int r0 = blockIdx.x * 500;
    int rend = r0 + 500; if (rend > N_NODES) rend = N_NODES;
    float s1 = 0.f, s2 = 0.f;
    for (int r = r0 + half; r < rend; r += 2) {
        float v = b2f(h[(size_t)r * HC + c]);
        s1 += v; s2 += v * v;
    }
    atomicAdd(&bnsum[c], s1);
    atomicAdd(&bnsq[c], s2);
}

// ==========================================================================
extern "C" void kernel_launch(void* const* d_in, const int* in_sizes, int n_in,
                              void* d_out, int out_size, void* d_ws, size_t ws_size,
                              hipStream_t stream) {
    const void* x_in = d_in[0];
    const int*  edge = (const int*)d_in[1];
    const int* esrc = edge;
    const int* edst = edge + N_EDGES;

    // ---- d_ws layout ----
    bf16* xbh  = (bf16*)d_ws;                              // MP*128 bf16 (h)
    bf16* xs   = xbh + (size_t)MP * HC;                    // MP*128 bf16
    bf16* scA  = xs + (size_t)MP * HC;                     // MP*8  bf16
    bf16* xlin = scA + (size_t)MP * 8;                     // MP*128 bf16
    bf16* Bp0  = xlin + (size_t)MP * HC;                   // BP_ELEMS bf16
    bf16* Bp1  = Bp0 + BP_ELEMS;                           // BP_ELEMS bf16
    bf16* fcWp = Bp1 + BP_ELEMS;                           // FC_ELEMS bf16
    float* bnstat = (float*)(fcWp + FC_ELEMS);             // 4*128 f32 [s0,q0,s1,q1]
    int*   flag  = (int*)(bnstat + 512);                   // 1 (+pad)
    int*   bsum  = flag + 4;                               // SCANB (150)
    float* parms = (float*)(bsum + SCANB + 2);             // NPARAM f32
    // param block offsets (input order)
    float* Wsrc_f  = parms;             // 2*16384
    float* Wdst_f  = parms + 32768;
    float* asrc_f  = parms + 65536;
    float* adst_f  = parms + 65792;
    float* cbias_f = parms + 66048;
    float* linW_f  = parms + 66304;
    float* linb_f  = parms + 99072;
    float* gamma_f = parms + 99328;
    float* beta_f  = parms + 99584;
    float* fcW_f   = parms + 99840;     // 128*349
    float* fcb_f   = parms + 144512;    // 349

    // ---- d_out scratch (dead before gemm_mfma_out writes) ----
    int* srcs    = (int*)d_out;                            // 6.4 MB
    int* offsets = srcs + N_EDGES;                         // 0.4 MB (segment ends)
    uint32_t* sorted = (uint32_t*)(offsets + N_NODES);     // 6.4 MB bucket-sorted packed edges
    int* cnt = (int*)(sorted + N_EDGES);                   // NTOT (1.2 MB) count/base matrix

    detect_dtype<<<1, 64, 0, stream>>>((const uint32_t*)x_in, flag, bnstat);

    cvt_params<<<(NPARAM + 255) / 256, 256, 0, stream>>>(
        d_in[2], d_in[3], d_in[4], d_in[5], d_in[6], d_in[7], d_in[8],
        d_in[9], d_in[10], d_in[11], d_in[12], parms, flag);

    // ---- CSR build: atomic-free two-level bucket sort (stream-ordered phases) ----
    bucket_hist<<<NCHUNK, 256, 0, stream>>>(edst, cnt);
    scan_partial<<<SCANB, 256, 0, stream>>>(cnt, bsum, NTOT);
    scan_final<<<SCANB, 256, 0, stream>>>(cnt, bsum, NTOT);
    bucket_scatter<<<NCHUNK, 256, 0, stream>>>(esrc, edst, cnt, sorted);
    bucket_csr<<<NBKT, 256, 0, stream>>>(sorted, cnt, srcs, offsets);

    pack_all<<<(PACK_TOTAL + 255) / 256, 256, 0, stream>>>(
        Wsrc_f, Wdst_f, asrc_f, adst_f, linW_f, fcW_f, Bp0, Bp1, fcWp);

    for (int layer = 0; layer < NUM_LAYERS; layer++) {
        const int boff = layer * HC;
        float* bns = bnstat + layer * 256;       // sum
        float* bnq = bns + 128;                  // sumsq

        if (layer == 0) {
            gemm_mfma_proj<0><<<MP / 64, 256, 0, stream>>>(
                x_in, flag, Bp0, xs, scA, xlin, nullptr, nullptr, nullptr, nullptr);
        } else {
            float* pbns = bnstat + (layer - 1) * 256;
            gemm_mfma_proj<1><<<MP / 64, 256, 0, stream>>>(
                xbh, nullptr, Bp1, xs, scA, xlin,
                gamma_f + (layer - 1) * HC, beta_f + (layer - 1) * HC,
                pbns, pbns + 128);
        }

        // h overwrites the xbh region (stream-ordered; gat_gather reads only xs/scA/xlin)
        gat_gather<<<N_NODES / 4, 256, 0, stream>>>(
            srcs, offsets, xs, scA, xlin, cbias_f + boff, linb_f + boff, xbh);

        bn_stats<<<200, 256, 0, stream>>>(xbh, bns, bnq);
    }

    gemm_mfma_out<<<MP / 64, 256, 0, stream>>>(
        xbh, fcWp, fcb_f, gamma_f + HC, beta_f + HC,
        bnstat + 256, bnstat + 256 + 128, d_out, flag);
}